// Round 8
// baseline (164.619 us; speedup 1.0000x reference)
//
#include <hip/hip_runtime.h>
#include <hip/hip_bf16.h>
#include <cstdint>

// Problem: B=32, T1=T2=512, D=128, gamma=1.0
// out[b] = softDTW( 1 - cos_sim(x[b], y[b]) )
//
// ws layout (floats):
//   invnx : 32*512            =     16,384
//   invny : 32*512            =     16,384
//   skew  : 32*1023*512       = 16,760,832   (cost/ln2 in anti-diagonal layout)

#define BT      32
#define TLEN    512
#define DF      128
#define NDIAG   1023          // kd = 0..1022  (kd = i-1 + j-1)
#define BIGV    1e30f
#define INV_LN2 1.44269504088896340f
#define LN2     0.69314718055994531f

// ------------------------------------------------------------- inverse norms
__global__ __launch_bounds__(256) void sdtw_invnorm(const float* __restrict__ x,
                                                    const float* __restrict__ y,
                                                    float* __restrict__ ox,
                                                    float* __restrict__ oy) {
    const float* in  = blockIdx.y ? y : x;
    float*       out = blockIdx.y ? oy : ox;
    int row = blockIdx.x * 4 + (threadIdx.x >> 6);
    int t   = threadIdx.x & 63;
    const float2* ip = reinterpret_cast<const float2*>(in + (size_t)row * DF);
    float2 v = ip[t];
    float s = v.x * v.x + v.y * v.y;
    #pragma unroll
    for (int o = 32; o; o >>= 1) s += __shfl_xor(s, o);
    if (t == 0) out[row] = 1.0f / fmaxf(sqrtf(s), 1e-12f);
}

// ------------------------------------------------- cosine-dist GEMM -> skew
#define KC   32
#define SPAD 132

__global__ __launch_bounds__(256) void sdtw_gemm_skew(const float* __restrict__ x,
                                                      const float* __restrict__ y,
                                                      const float* __restrict__ invnx,
                                                      const float* __restrict__ invny,
                                                      float* __restrict__ skew) {
    __shared__ float smem[16640];
    float* xs = smem;                        // [KC][SPAD] transposed: xs[k][row]
    float* ys = smem + KC * SPAD;

    const int b  = blockIdx.z;
    const int r0 = blockIdx.y * 128;
    const int c0 = blockIdx.x * 128;
    const int tid = threadIdx.x;
    const int tx = tid & 15, ty = tid >> 4;

    const float* xb = x + ((size_t)b * TLEN + r0) * DF;
    const float* yb = y + ((size_t)b * TLEN + c0) * DF;

    float acc[8][8];
    #pragma unroll
    for (int i = 0; i < 8; ++i)
        #pragma unroll
        for (int j = 0; j < 8; ++j) acc[i][j] = 0.0f;

    for (int kb = 0; kb < DF; kb += KC) {
        __syncthreads();
        #pragma unroll
        for (int i = 0; i < 4; ++i) {
            int g   = tid + i * 256;
            int row = g >> 3;
            int kq  = g & 7;
            float4 vx = *reinterpret_cast<const float4*>(xb + (size_t)row * DF + kb + kq * 4);
            float4 vy = *reinterpret_cast<const float4*>(yb + (size_t)row * DF + kb + kq * 4);
            xs[(kq * 4 + 0) * SPAD + row] = vx.x;
            xs[(kq * 4 + 1) * SPAD + row] = vx.y;
            xs[(kq * 4 + 2) * SPAD + row] = vx.z;
            xs[(kq * 4 + 3) * SPAD + row] = vx.w;
            ys[(kq * 4 + 0) * SPAD + row] = vy.x;
            ys[(kq * 4 + 1) * SPAD + row] = vy.y;
            ys[(kq * 4 + 2) * SPAD + row] = vy.z;
            ys[(kq * 4 + 3) * SPAD + row] = vy.w;
        }
        __syncthreads();
        #pragma unroll
        for (int k = 0; k < KC; ++k) {
            float ax[8], ay[8];
            *reinterpret_cast<float4*>(&ax[0]) = *reinterpret_cast<const float4*>(&xs[k * SPAD + ty * 8]);
            *reinterpret_cast<float4*>(&ax[4]) = *reinterpret_cast<const float4*>(&xs[k * SPAD + ty * 8 + 4]);
            *reinterpret_cast<float4*>(&ay[0]) = *reinterpret_cast<const float4*>(&ys[k * SPAD + tx * 8]);
            *reinterpret_cast<float4*>(&ay[4]) = *reinterpret_cast<const float4*>(&ys[k * SPAD + tx * 8 + 4]);
            #pragma unroll
            for (int i = 0; i < 8; ++i)
                #pragma unroll
                for (int j = 0; j < 8; ++j)
                    acc[i][j] = fmaf(ax[i], ay[j], acc[i][j]);
        }
    }

    // epilogue: (1 - dot*invnx*invny)/ln2 into LDS tile [128][130]
    float rn[8], cn[8];
    #pragma unroll
    for (int i = 0; i < 8; ++i) rn[i] = invnx[b * TLEN + r0 + ty * 8 + i];
    #pragma unroll
    for (int j = 0; j < 8; ++j) cn[j] = invny[b * TLEN + c0 + tx * 8 + j];

    __syncthreads();
    float* cs = smem;
    #pragma unroll
    for (int i = 0; i < 8; ++i)
        #pragma unroll
        for (int j = 0; j < 8; ++j)
            cs[(ty * 8 + i) * 130 + tx * 8 + j] =
                (1.0f - acc[i][j] * rn[i] * cn[j]) * INV_LN2;
    __syncthreads();

    float* sk = skew + (size_t)b * (NDIAG * TLEN);
    const int wv = tid >> 6, l = tid & 63;
    for (int dd = wv; dd < 255; dd += 4) {
        int lo = max(0, dd - 127), hi = min(127, dd);
        size_t base = (size_t)(r0 + c0 + dd) * TLEN + r0;
        for (int rb = lo; rb <= hi; rb += 64) {
            int rl = rb + l;
            if (rl <= hi) sk[base + rl] = cs[rl * 129 + dd];   // rl*130 + (dd-rl)
        }
    }
}

// ----------------------------------------------------------------- DTW DP
// 8 waves per batch (512 threads), lane owns row r = tid; wave w processes
// diag kd at phase p = kd + 16w; one __syncthreads per 16-phase segment.
// Segment modes (wave-uniform): JUNK / PARTIAL(masked+clamped) / INTERIOR.
// R7 changes:
//  - double-buffered SEGMENT-BATCHED cost loads: all 16 loads for the NEXT
//    segment issue at segment start (named regs A_*/B_*, parity = sw&1), so
//    the pre-barrier vmcnt(0) drain hits ~800cy-old loads -> free.
//  - lane-0 patch folded into DPP: up_ = update_dpp(old=bd_up, PN,
//    wave_shr:1, bound_ctrl=false) -> lane0 receives bd_up, no cndmask.
//    And dg(s+1) == up(s) (patched) -> dgs carries it; bd_dg eliminated.

__device__ __forceinline__ int clampi(int v) {
    return v < 0 ? 0 : (v > NDIAG - 1 ? NDIAG - 1 : v);
}

__device__ __forceinline__ float dpp_shr1_old(float old, float x) {
    return __builtin_bit_cast(float,
        __builtin_amdgcn_update_dpp(__builtin_bit_cast(int, old),
                                    __builtin_bit_cast(int, x),
                                    0x138 /*wave_shr:1*/, 0xF, 0xF, false));
}

#define PH(s, CC, PN, PO, NQC, MASKED)                                         \
  {                                                                            \
    float up_ = dpp_shr1_old(bd_up, PN);     /* lane0 <- bd_up */              \
    float dg_ = dgs;                         /* == patched up_ of prev phase */\
    float m_   = fminf(fminf(dg_, PN), up_);                                   \
    float mid_ = __builtin_amdgcn_fmed3f(dg_, PN, up_);                        \
    float mx_  = fmaxf(fmaxf(dg_, PN), up_);                                   \
    float e_   = 1.0f + __builtin_amdgcn_exp2f(m_ - mid_)                      \
                      + __builtin_amdgcn_exp2f(m_ - mx_);                      \
    float v_   = CC + m_ - __builtin_amdgcn_logf(e_);                          \
    PO = (MASKED) ? (((unsigned)(vb0 + (s)) < 512u) ? v_ : vBig) : v_;         \
    if (((s) & 3) == 0) bq.x = PO;                                             \
    if (((s) & 3) == 1) bq.y = PO;                                             \
    if (((s) & 3) == 2) bq.z = PO;                                             \
    if (((s) & 3) == 3) { bq.w = PO;                                           \
      if (lt == 63) bnd4[w + 1][(q0 + ((s) >> 2)) & 7] = bq; }                 \
    bd_up = (NQC);                                                             \
    dgs = up_;                                                                 \
  }

#define BODY16(CUR, MASKED)                                                    \
    PH(0,  CUR##0,  P, Q, nq0.x, MASKED) PH(1,  CUR##1,  Q, P, nq0.y, MASKED)  \
    PH(2,  CUR##2,  P, Q, nq0.z, MASKED) PH(3,  CUR##3,  Q, P, nq0.w, MASKED)  \
    PH(4,  CUR##4,  P, Q, nq1.x, MASKED) PH(5,  CUR##5,  Q, P, nq1.y, MASKED)  \
    PH(6,  CUR##6,  P, Q, nq1.z, MASKED) PH(7,  CUR##7,  Q, P, nq1.w, MASKED)  \
    PH(8,  CUR##8,  P, Q, nq2.x, MASKED) PH(9,  CUR##9,  Q, P, nq2.y, MASKED)  \
    PH(10, CUR##10, P, Q, nq2.z, MASKED) PH(11, CUR##11, Q, P, nq2.w, MASKED)  \
    PH(12, CUR##12, P, Q, nq3.x, MASKED) PH(13, CUR##13, Q, P, nq3.y, MASKED)  \
    PH(14, CUR##14, P, Q, nq3.z, MASKED) PH(15, CUR##15, Q, P, nq3.w, MASKED)

#define LD16_F(R, KB)                                                          \
    R##0  = skb[(size_t)((KB) + 0)  * TLEN];                                   \
    R##1  = skb[(size_t)((KB) + 1)  * TLEN];                                   \
    R##2  = skb[(size_t)((KB) + 2)  * TLEN];                                   \
    R##3  = skb[(size_t)((KB) + 3)  * TLEN];                                   \
    R##4  = skb[(size_t)((KB) + 4)  * TLEN];                                   \
    R##5  = skb[(size_t)((KB) + 5)  * TLEN];                                   \
    R##6  = skb[(size_t)((KB) + 6)  * TLEN];                                   \
    R##7  = skb[(size_t)((KB) + 7)  * TLEN];                                   \
    R##8  = skb[(size_t)((KB) + 8)  * TLEN];                                   \
    R##9  = skb[(size_t)((KB) + 9)  * TLEN];                                   \
    R##10 = skb[(size_t)((KB) + 10) * TLEN];                                   \
    R##11 = skb[(size_t)((KB) + 11) * TLEN];                                   \
    R##12 = skb[(size_t)((KB) + 12) * TLEN];                                   \
    R##13 = skb[(size_t)((KB) + 13) * TLEN];                                   \
    R##14 = skb[(size_t)((KB) + 14) * TLEN];                                   \
    R##15 = skb[(size_t)((KB) + 15) * TLEN];

#define LD16_C(R, KB)                                                          \
    R##0  = skb[(size_t)clampi((KB) + 0)  * TLEN];                             \
    R##1  = skb[(size_t)clampi((KB) + 1)  * TLEN];                             \
    R##2  = skb[(size_t)clampi((KB) + 2)  * TLEN];                             \
    R##3  = skb[(size_t)clampi((KB) + 3)  * TLEN];                             \
    R##4  = skb[(size_t)clampi((KB) + 4)  * TLEN];                             \
    R##5  = skb[(size_t)clampi((KB) + 5)  * TLEN];                             \
    R##6  = skb[(size_t)clampi((KB) + 6)  * TLEN];                             \
    R##7  = skb[(size_t)clampi((KB) + 7)  * TLEN];                             \
    R##8  = skb[(size_t)clampi((KB) + 8)  * TLEN];                             \
    R##9  = skb[(size_t)clampi((KB) + 9)  * TLEN];                             \
    R##10 = skb[(size_t)clampi((KB) + 10) * TLEN];                             \
    R##11 = skb[(size_t)clampi((KB) + 11) * TLEN];                             \
    R##12 = skb[(size_t)clampi((KB) + 12) * TLEN];                             \
    R##13 = skb[(size_t)clampi((KB) + 13) * TLEN];                             \
    R##14 = skb[(size_t)clampi((KB) + 14) * TLEN];                             \
    R##15 = skb[(size_t)clampi((KB) + 15) * TLEN];

__global__ __launch_bounds__(512) void sdtw_dp(const float* __restrict__ skew,
                                               float* __restrict__ out) {
    const int b   = blockIdx.x;
    const int tid = threadIdx.x;
    const int w   = tid >> 6;
    const int lt  = tid & 63;
    const float* skb = skew + (size_t)b * (NDIAG * TLEN) + tid;   // row r = tid

    __shared__ float4 bnd4[9][8];                // [consumer wave][quad slot]
    if (tid < 288) ((float*)bnd4)[tid] = BIGV;

    float P = BIGV, Q = BIGV;
    float vBig  = BIGV;
    float bd_up = BIGV;
    // dgs: patched up_ of the previous phase. First real use: (w0,lane0) at
    // kd=0 must see R(0,0)=0; everyone else BIGV (w>0 rebuilt in warm-up).
    float dgs   = (tid == 0) ? 0.0f : BIGV;
    float4 bq = make_float4(BIGV, BIGV, BIGV, BIGV);

    float A_0 = 0, A_1 = 0, A_2 = 0, A_3 = 0, A_4 = 0, A_5 = 0, A_6 = 0, A_7 = 0,
          A_8 = 0, A_9 = 0, A_10 = 0, A_11 = 0, A_12 = 0, A_13 = 0, A_14 = 0, A_15 = 0;
    float B_0 = 0, B_1 = 0, B_2 = 0, B_3 = 0, B_4 = 0, B_5 = 0, B_6 = 0, B_7 = 0,
          B_8 = 0, B_9 = 0, B_10 = 0, B_11 = 0, B_12 = 0, B_13 = 0, B_14 = 0, B_15 = 0;

    __syncthreads();

    // prime B for wave 0's first segment (sw=0 consumes B); harmless for w>0
    LD16_C(B_, 0)

    for (int s = 0; s < 71; ++s) {
        const int sw  = s - 5 * w;               // wave-uniform
        const int kd0 = 16 * (s - w);
        const int q0  = (kd0 >> 2) & 7;
        const int vb0 = kd0 - tid;

        if (sw >= -1 && sw <= 35) {
            // hoisted boundary quads (all written in segment s-1 -> race-free)
            float4 nq0 = bnd4[w][q0];
            float4 nq1 = bnd4[w][(q0 + 1) & 7];
            float4 nq2 = bnd4[w][(q0 + 2) & 7];
            float4 nq3 = bnd4[w][(q0 + 3) & 7];
            const bool consumeA = (sw & 1) != 0; // sw=-1 -> consume A (garbage, masked)
            if (sw >= 4 && sw <= 31) {           // interior: no mask, no clamp
                if (consumeA) { LD16_F(B_, kd0 + 16) BODY16(A_, 0) }
                else          { LD16_F(A_, kd0 + 16) BODY16(B_, 0) }
            } else {                             // warm-up / staircase
                if (consumeA) { LD16_C(B_, kd0 + 16) BODY16(A_, 1) }
                else          { LD16_C(A_, kd0 + 16) BODY16(B_, 1) }
            }
        } else {
            if (lt == 63) {                      // junk: keep boundary cadence
                float4 bigq = make_float4(BIGV, BIGV, BIGV, BIGV);
                bnd4[w + 1][q0]           = bigq;
                bnd4[w + 1][(q0 + 1) & 7] = bigq;
                bnd4[w + 1][(q0 + 2) & 7] = bigq;
                bnd4[w + 1][(q0 + 3) & 7] = bigq;
            }
        }
        __syncthreads();
    }

    if (tid == 511) out[b] = Q * LN2;            // R'(512,512) * ln2
}

// ---------------------------------------------------------------- launcher
extern "C" void kernel_launch(void* const* d_in, const int* in_sizes, int n_in,
                              void* d_out, int out_size, void* d_ws, size_t ws_size,
                              hipStream_t stream) {
    const float* x = (const float*)d_in[0];
    const float* y = (const float*)d_in[1];
    float* outp = (float*)d_out;

    float* invnx = (float*)d_ws;                          //  16,384 floats
    float* invny = invnx + (size_t)BT * TLEN;             //  16,384 floats
    float* skew  = invny + (size_t)BT * TLEN;             //  16,760,832 floats

    sdtw_invnorm<<<dim3(BT * TLEN / 4, 2), dim3(256), 0, stream>>>(x, y, invnx, invny);
    sdtw_gemm_skew<<<dim3(4, 4, BT), dim3(256), 0, stream>>>(x, y, invnx, invny, skew);
    sdtw_dp<<<dim3(BT), dim3(512), 0, stream>>>(skew, outp);
}